// Round 3
// baseline (480.506 us; speedup 1.0000x reference)
//
#include <hip/hip_runtime.h>
#include <hip/hip_bf16.h>
#include <math.h>

// Problem constants (fixed by the reference's setup_inputs)
#define BB 4
#define TT 2048
#define DD 384
#define HH 192
#define TOTAL_LEN 65536                 // B*T*8 (static output length)
#define EXP_ELEMS (BB * TOTAL_LEN * DD) // 100,663,296 floats
#define F4_PER_ROW (DD / 4)             // 96
#define TOTAL_F4 (BB * TOTAL_LEN * F4_PER_ROW) // 25,165,824

typedef float f32x4 __attribute__((ext_vector_type(4)));

// ---------------------------------------------------------------------------
// K1: 2-layer MLP duration head, R=8 rows/wave, NO LDS.
// 256 blocks x 256 threads = 1 block/CU; wave w owns rows row0+8w..+7,
// lane l owns h-columns {l, l+64, l+128}.
// x rows are wave-uniform -> readfirstlane'd pointer lets the compiler use
// scalar (SMEM) loads: no LDS staging, no barriers, x streamed once (12.6 MB).
// w1 sweep: 294 KB per wave, 4 waves/CU = 1.18 MB/CU (~7.7 us L1 service),
// balancing the 7.7 us chip VALU floor (604M lane-FMAs).
// acc 24 + w 12 regs -> ~64 VGPR, no spill.
// ---------------------------------------------------------------------------
__global__ __launch_bounds__(256) void mlp_dur_kernel(
    const float* __restrict__ x, const float* __restrict__ w1,
    const float* __restrict__ b1, const float* __restrict__ w2,
    const float* __restrict__ b2, float* __restrict__ dur_out,
    int* __restrict__ dur0) {
  const int tid = threadIdx.x;
  const int lane = tid & 63;
  const int wave = tid >> 6;
  const int row0 = blockIdx.x * 32 + wave * 8;

  // Wave-uniform base pointer for this wave's 8 x-rows (enables s_load).
  const int urow0 = __builtin_amdgcn_readfirstlane(row0);
  const float* __restrict__ xw = x + (size_t)urow0 * DD;

  float acc[8][3];
#pragma unroll
  for (int r = 0; r < 8; ++r)
#pragma unroll
    for (int c = 0; c < 3; ++c) acc[r][c] = 0.f;

#pragma unroll 2
  for (int k = 0; k < DD; k += 4) {
    float w[4][3];
#pragma unroll
    for (int kk = 0; kk < 4; ++kk)
#pragma unroll
      for (int c = 0; c < 3; ++c)
        w[kk][c] = w1[(size_t)(k + kk) * HH + lane + 64 * c];
    f32x4 xv[8];
#pragma unroll
    for (int r = 0; r < 8; ++r)
      xv[r] = *(const f32x4*)(xw + (size_t)r * DD + k); // uniform -> scalar ld
#pragma unroll
    for (int r = 0; r < 8; ++r)
#pragma unroll
      for (int kk = 0; kk < 4; ++kk)
#pragma unroll
        for (int c = 0; c < 3; ++c)
          acc[r][c] = fmaf(xv[r][kk], w[kk][c], acc[r][c]);
  }

  // Layer 2: z[row] = sum_j relu(h)*w2[j] + b2, then softplus/clamp/round.
  float b1v[3], w2v[3];
#pragma unroll
  for (int c = 0; c < 3; ++c) {
    b1v[c] = b1[lane + 64 * c];
    w2v[c] = w2[lane + 64 * c];
  }
#pragma unroll
  for (int r = 0; r < 8; ++r) {
    float s = 0.f;
#pragma unroll
    for (int c = 0; c < 3; ++c)
      s += fmaxf(acc[r][c] + b1v[c], 0.f) * w2v[c];
#pragma unroll
    for (int off = 32; off > 0; off >>= 1) s += __shfl_down(s, off, 64);
    if (lane == 0) {
      const float z = s + b2[0];
      const float sp = fmaxf(z, 0.f) + log1pf(expf(-fabsf(z))); // stable softplus
      const float dur = rintf(fmaxf(sp, 8.0f)); // round-half-even == jnp.round
      const int row = row0 + r;
      dur_out[row] = dur;
      if (row < TT) dur0[row] = (int)dur; // batch-0 durations drive expansion
    }
  }
}

// ---------------------------------------------------------------------------
// K2: fused scan + searchsorted. 256 blocks x 256 threads; every block
// recomputes the 2048-int inclusive scan in LDS (8 KB dur0 read per block),
// then each thread binary-searches its position in LDS.
// Each block covers 256 positions -> grid = TOTAL_LEN/256 = 256 blocks.
// ---------------------------------------------------------------------------
__global__ __launch_bounds__(256) void idx_kernel(const int* __restrict__ dur0,
                                                  int* __restrict__ idx_map) {
  __shared__ int cum[TT];   // 8 KB
  __shared__ int wsum[256]; // 1 KB
  const int tid = threadIdx.x;

  const int4* d4 = (const int4*)dur0;
  const int4 a = d4[tid * 2];
  const int4 b = d4[tid * 2 + 1];
  int v[8] = {a.x, a.y, a.z, a.w, b.x, b.y, b.z, b.w};
  int run = 0;
#pragma unroll
  for (int i = 0; i < 8; ++i) {
    run += v[i];
    v[i] = run;
  }
  wsum[tid] = run;
  __syncthreads();
  for (int off = 1; off < 256; off <<= 1) {
    const int t = (tid >= off) ? wsum[tid - off] : 0;
    __syncthreads();
    wsum[tid] += t;
    __syncthreads();
  }
  const int excl = wsum[tid] - run;
  const int base = tid * 8;
#pragma unroll
  for (int i = 0; i < 8; ++i) cum[base + i] = v[i] + excl;
  __syncthreads();

  const int total = cum[TT - 1];
  const int pos = blockIdx.x * 256 + tid;
  int lo = 0, hi = TT - 1; // smallest t with cum[t] > pos
  while (lo < hi) {
    const int mid = (lo + hi) >> 1;
    if (cum[mid] > pos) hi = mid;
    else lo = mid + 1;
  }
  idx_map[pos] = (pos < total) ? lo : -1;
}

// ---------------------------------------------------------------------------
// K3: expansion. 8192 blocks x 256 threads x 12 f32x4. Block-contiguous:
// each block owns exactly 3072 f32x4 = 32 output rows = 4 source x-rows
// (8x expansion), so idx_map and the x gather are L1-hot within the block.
// Coalesced nontemporal 16 B stores (output 384 MiB >> L2; don't pollute).
// out[b, pos, :] = (idx_map[pos] >= 0) ? x[b, idx_map[pos], :] : 0
// ---------------------------------------------------------------------------
__global__ __launch_bounds__(256) void expand_kernel(
    const f32x4* __restrict__ x4, const int* __restrict__ idx_map,
    f32x4* __restrict__ out4) {
  unsigned t = blockIdx.x * 3072u + threadIdx.x;
#pragma unroll 4
  for (int i = 0; i < 12; ++i, t += 256u) {
    const unsigned row = t / 96u; // magic-mul division
    const unsigned col = t - row * 96u;
    const unsigned b = row >> 16; // TOTAL_LEN = 65536
    const unsigned pos = row & 65535u;
    const int id = idx_map[pos]; // broadcast across the 96 lanes of a row
    f32x4 v = {0.f, 0.f, 0.f, 0.f};
    if (id >= 0) v = x4[((size_t)b * TT + (unsigned)id) * F4_PER_ROW + col];
    // Must write zeros past the valid total: the timed loop does not re-zero.
    __builtin_nontemporal_store(v, out4 + t);
  }
}

extern "C" void kernel_launch(void* const* d_in, const int* in_sizes, int n_in,
                              void* d_out, int out_size, void* d_ws,
                              size_t ws_size, hipStream_t stream) {
  const float* x = (const float*)d_in[0];
  const float* w1 = (const float*)d_in[1];
  const float* b1 = (const float*)d_in[2];
  const float* w2 = (const float*)d_in[3];
  const float* b2 = (const float*)d_in[4];
  // d_in[5] = total_length scalar; static (65536) by construction.

  float* out = (float*)d_out;
  float* dur_out = out + (size_t)EXP_ELEMS; // output 1: (B, T) durations

  int* ws = (int*)d_ws;
  int* dur0 = ws;             // 2048 ints
  int* idx_map = ws + 2 * TT; // 65536 ints

  mlp_dur_kernel<<<256, 256, 0, stream>>>(x, w1, b1, w2, b2, dur_out, dur0);
  idx_kernel<<<TOTAL_LEN / 256, 256, 0, stream>>>(dur0, idx_map);
  expand_kernel<<<TOTAL_F4 / 3072, 256, 0, stream>>>((const f32x4*)x, idx_map,
                                                     (f32x4*)out);
}

// Round 4
// 448.926 us; speedup vs baseline: 1.0703x; 1.0703x over previous
//
#include <hip/hip_runtime.h>
#include <hip/hip_bf16.h>
#include <math.h>

// Problem constants (fixed by the reference's setup_inputs)
#define BB 4
#define TT 2048
#define DD 384
#define HH 192
#define TOTAL_LEN 65536                 // B*T*8 (static output length)
#define EXP_ELEMS (BB * TOTAL_LEN * DD) // 100,663,296 floats
#define F4_PER_ROW (DD / 4)             // 96
#define TOTAL_F4 (BB * TOTAL_LEN * F4_PER_ROW) // 25,165,824
#define ROWS_PER_BLK 16

typedef float f32x4 __attribute__((ext_vector_type(4)));

// ---------------------------------------------------------------------------
// K1: 2-layer MLP duration head — EXACT round-0 structure (measured-good).
// 512 blocks x 256 threads; block stages 16 x-rows in LDS (24 KB).
// Thread j<192 owns h-column j: acc[16] registers, w1 reads coalesced
// (thread j -> w1[k*192+j]) and shared across the 16 rows; w1 swept once per
// block (588 KB/CU L2 traffic). LDS x reads are wave-uniform -> broadcast
// (cheap: round-2 evidence shows cutting them 4x gained nothing).
// ---------------------------------------------------------------------------
__global__ __launch_bounds__(256) void mlp_dur_kernel(
    const float* __restrict__ x, const float* __restrict__ w1,
    const float* __restrict__ b1, const float* __restrict__ w2,
    const float* __restrict__ b2, float* __restrict__ dur_out,
    int* __restrict__ dur0) {
  __shared__ float xs[ROWS_PER_BLK * DD]; // 24 KB
  __shared__ float part[ROWS_PER_BLK * 4];

  const int tid = threadIdx.x;
  const int lane = tid & 63;
  const int wave = tid >> 6;
  const int row0 = blockIdx.x * ROWS_PER_BLK;

  // Stage 16 rows (1536 float4) coalesced into LDS.
  const f32x4* xg = (const f32x4*)(x + (size_t)row0 * DD);
  f32x4* xs4 = (f32x4*)xs;
#pragma unroll
  for (int i = 0; i < 6; ++i) xs4[i * 256 + tid] = xg[i * 256 + tid];
  __syncthreads();

  float acc[ROWS_PER_BLK];
#pragma unroll
  for (int r = 0; r < ROWS_PER_BLK; ++r) acc[r] = 0.f;

  const int j = tid;
  if (j < HH) {
    for (int k = 0; k < DD; k += 4) {
      float w[4];
#pragma unroll
      for (int kk = 0; kk < 4; ++kk) w[kk] = w1[(size_t)(k + kk) * HH + j];
#pragma unroll
      for (int r = 0; r < ROWS_PER_BLK; ++r) {
        const float* xr = xs + r * DD + k;
#pragma unroll
        for (int kk = 0; kk < 4; ++kk) acc[r] = fmaf(xr[kk], w[kk], acc[r]);
      }
    }
  }

  // Phase 2: p[r] = relu(acc[r]+b1[j]) * w2[j]; reduce over j across block.
  const float b1v = (j < HH) ? b1[j] : 0.f;
  const float w2v = (j < HH) ? w2[j] : 0.f;

#pragma unroll
  for (int r = 0; r < ROWS_PER_BLK; ++r) {
    float s = fmaxf(acc[r] + b1v, 0.f) * w2v; // j>=192: acc=0,w2v=0 -> 0
#pragma unroll
    for (int off = 32; off > 0; off >>= 1) s += __shfl_down(s, off, 64);
    if (lane == 0) part[r * 4 + wave] = s;
  }
  __syncthreads();

  if (tid < ROWS_PER_BLK) {
    const float z = part[tid * 4] + part[tid * 4 + 1] + part[tid * 4 + 2] +
                    part[tid * 4 + 3] + b2[0];
    const float sp = fmaxf(z, 0.f) + log1pf(expf(-fabsf(z))); // stable softplus
    const float dur = rintf(fmaxf(sp, 8.0f)); // round-half-even == jnp.round
    const int row = row0 + tid;
    dur_out[row] = dur;
    if (row < TT) dur0[row] = (int)dur; // batch-0 durations drive expansion
  }
}

// ---------------------------------------------------------------------------
// K2: fused scan + searchsorted (proven correct rounds 2-3). 256 blocks x
// 256 threads; every block recomputes the 2048-int inclusive scan in LDS
// (8 KB dur0 read per block = 2 MB L2 total, trivial), then each thread
// binary-searches its position in LDS. Removes the serial single-block scan
// kernel + one launch gap. Grid = TOTAL_LEN/256 = 256 blocks.
// ---------------------------------------------------------------------------
__global__ __launch_bounds__(256) void idx_kernel(const int* __restrict__ dur0,
                                                  int* __restrict__ idx_map) {
  __shared__ int cum[TT];   // 8 KB
  __shared__ int wsum[256]; // 1 KB
  const int tid = threadIdx.x;

  const int4* d4 = (const int4*)dur0;
  const int4 a = d4[tid * 2];
  const int4 b = d4[tid * 2 + 1];
  int v[8] = {a.x, a.y, a.z, a.w, b.x, b.y, b.z, b.w};
  int run = 0;
#pragma unroll
  for (int i = 0; i < 8; ++i) {
    run += v[i];
    v[i] = run;
  }
  wsum[tid] = run;
  __syncthreads();
  for (int off = 1; off < 256; off <<= 1) {
    const int t = (tid >= off) ? wsum[tid - off] : 0;
    __syncthreads();
    wsum[tid] += t;
    __syncthreads();
  }
  const int excl = wsum[tid] - run;
  const int base = tid * 8;
#pragma unroll
  for (int i = 0; i < 8; ++i) cum[base + i] = v[i] + excl;
  __syncthreads();

  const int total = cum[TT - 1];
  const int pos = blockIdx.x * 256 + tid;
  int lo = 0, hi = TT - 1; // smallest t with cum[t] > pos
  while (lo < hi) {
    const int mid = (lo + hi) >> 1;
    if (cum[mid] > pos) hi = mid;
    else lo = mid + 1;
  }
  idx_map[pos] = (pos < total) ? lo : -1;
}

// ---------------------------------------------------------------------------
// K3: expansion — EXACT round-0 structure (measured-good). One float4 per
// lane, 98304 blocks: strict sequential block-order write sweep of the
// 403 MB output (DRAM-page friendly), coalesced nontemporal stores.
// Both attempted restructures (grid-stride 48-deep; 12-deep block chunks)
// regressed ~10-17 us — do not perturb the write order.
// out[b, pos, :] = (idx_map[pos] >= 0) ? x[b, idx_map[pos], :] : 0
// ---------------------------------------------------------------------------
__global__ __launch_bounds__(256) void expand_kernel(
    const f32x4* __restrict__ x4, const int* __restrict__ idx_map,
    f32x4* __restrict__ out4) {
  const unsigned t = blockIdx.x * 256u + threadIdx.x;
  const unsigned row = t / 96u;       // magic-mul division
  const unsigned col = t - row * 96u;
  const unsigned b = row >> 16;       // TOTAL_LEN = 65536
  const unsigned pos = row & 65535u;
  const int id = idx_map[pos]; // broadcast across the 96 lanes of a row
  f32x4 v = {0.f, 0.f, 0.f, 0.f};
  if (id >= 0) v = x4[((size_t)b * TT + (unsigned)id) * F4_PER_ROW + col];
  __builtin_nontemporal_store(v, out4 + t);
}

extern "C" void kernel_launch(void* const* d_in, const int* in_sizes, int n_in,
                              void* d_out, int out_size, void* d_ws,
                              size_t ws_size, hipStream_t stream) {
  const float* x = (const float*)d_in[0];
  const float* w1 = (const float*)d_in[1];
  const float* b1 = (const float*)d_in[2];
  const float* w2 = (const float*)d_in[3];
  const float* b2 = (const float*)d_in[4];
  // d_in[5] = total_length scalar; static (65536) by construction.

  float* out = (float*)d_out;
  float* dur_out = out + (size_t)EXP_ELEMS; // output 1: (B, T) durations

  int* ws = (int*)d_ws;
  int* dur0 = ws;             // 2048 ints
  int* idx_map = ws + 2 * TT; // 65536 ints

  mlp_dur_kernel<<<512, 256, 0, stream>>>(x, w1, b1, w2, b2, dur_out, dur0);
  idx_kernel<<<TOTAL_LEN / 256, 256, 0, stream>>>(dur0, idx_map);
  expand_kernel<<<TOTAL_F4 / 256, 256, 0, stream>>>((const f32x4*)x, idx_map,
                                                    (f32x4*)out);
}